// Round 6
// baseline (392.689 us; speedup 1.0000x reference)
//
#include <hip/hip_runtime.h>
#include <math.h>

#define HIDDEN 768
#define NH 12
#define DH 64
#define SEQ 2048
#define BATCH 4

typedef __bf16 bf16;
typedef bf16 bf16x4 __attribute__((ext_vector_type(4)));
typedef bf16 bf16x8 __attribute__((ext_vector_type(8)));
typedef float f32x4 __attribute__((ext_vector_type(4)));

// Q pre-scale: 1/sqrt(64) * log2(e), so softmax is exp2(s) directly.
#define QSCALE 0.18033688011112042f

// ---------------------------------------------------------------------------
// prep_w: transpose weights. z<3: Wq/Wk/Wv -> Wt bf16 [2304][768] (1-term).
// z==3: Wo -> Wot hi/lo bf16 [768][768].
// ---------------------------------------------------------------------------
__global__ __launch_bounds__(256) void prep_w(const float* __restrict__ Wq,
                                              const float* __restrict__ Wk,
                                              const float* __restrict__ Wv,
                                              const float* __restrict__ Wo,
                                              bf16* __restrict__ Wt,
                                              bf16* __restrict__ Wot_hi,
                                              bf16* __restrict__ Wot_lo) {
    __shared__ float Ts[64][68];
    const int tid = threadIdx.x;
    const int n0 = blockIdx.x * 64, k0 = blockIdx.y * 64, z = blockIdx.z;
    const float* W = (z == 0) ? Wq : (z == 1) ? Wk : (z == 2) ? Wv : Wo;

    {
        const int r = tid >> 2, c = (tid & 3) << 4;
        const float* src = W + (size_t)(k0 + r) * HIDDEN + n0 + c;
#pragma unroll
        for (int j = 0; j < 4; ++j)
            *(float4*)&Ts[r][c + 4 * j] = *(const float4*)(src + 4 * j);
    }
    __syncthreads();

    const int nl = tid >> 2, kc = (tid & 3) << 4;
    float v[16];
#pragma unroll
    for (int j = 0; j < 16; ++j) v[j] = Ts[kc + j][nl];

    if (z < 3) {
        bf16 hi[16];
#pragma unroll
        for (int j = 0; j < 16; ++j) hi[j] = (bf16)v[j];
        const size_t off = (size_t)(z * HIDDEN + n0 + nl) * HIDDEN + k0 + kc;
        *(bf16x8*)(Wt + off) = *(bf16x8*)&hi[0];
        *(bf16x8*)(Wt + off + 8) = *(bf16x8*)&hi[8];
    } else {
        bf16 hi[16], lo[16];
#pragma unroll
        for (int j = 0; j < 16; ++j) {
            hi[j] = (bf16)v[j];
            lo[j] = (bf16)(v[j] - (float)hi[j]);
        }
        const size_t off = (size_t)(n0 + nl) * HIDDEN + k0 + kc;
        *(bf16x8*)(Wot_hi + off) = *(bf16x8*)&hi[0];
        *(bf16x8*)(Wot_hi + off + 8) = *(bf16x8*)&hi[8];
        *(bf16x8*)(Wot_lo + off) = *(bf16x8*)&lo[0];
        *(bf16x8*)(Wot_lo + off + 8) = *(bf16x8*)&lo[8];
    }
}

// ---------------------------------------------------------------------------
// QKV GEMM, 1-term bf16, A = X fp32 converted inline during staging
// (prep_x fused). 128x128 tile, register-prefetch double buffer.
// MFMA 16x16x32 layouts (HW-verified R1-R5):
//   A: lane=A[m=l16][k=quad*8+j]; B: lane=B[k=quad*8+j][n=l16];
//   C/D: lane=D[row=quad*4+reg][col=l16]
// ---------------------------------------------------------------------------
__global__ __launch_bounds__(256) void gemm_qkv(
    const float* __restrict__ X, const bf16* __restrict__ Wt,
    const float* __restrict__ bq, const float* __restrict__ bk,
    const float* __restrict__ bv, bf16* __restrict__ q_out,
    bf16* __restrict__ k_out, bf16* __restrict__ v_out) {
    __shared__ bf16 As[128][40];
    __shared__ bf16 Bs[128][40];

    const int tid = threadIdx.x;
    const int ln = tid & 63, wv = tid >> 6;
    const int quad = ln >> 4, l16 = ln & 15;
    const int wm = wv >> 1, wn = wv & 1;
    const int n0 = blockIdx.x * 128, m0 = blockIdx.y * 128;

    f32x4 acc[4][4];
#pragma unroll
    for (int i = 0; i < 4; ++i)
#pragma unroll
        for (int j = 0; j < 4; ++j) acc[i][j] = (f32x4){0.f, 0.f, 0.f, 0.f};

    const int sr = tid >> 1, sc = (tid & 1) << 4;
    const float* gA = X + (size_t)(m0 + sr) * HIDDEN + sc;
    const bf16* gB = Wt + (size_t)(n0 + sr) * HIDDEN + sc;

    float fa[16];
    bf16x8 br0, br1;
#pragma unroll
    for (int j = 0; j < 4; ++j) *(float4*)&fa[4 * j] = *(const float4*)(gA + 4 * j);
    br0 = *(const bf16x8*)gB;
    br1 = *(const bf16x8*)(gB + 8);

    for (int k0 = 0; k0 < HIDDEN; k0 += 32) {
        bf16 cv[16];
#pragma unroll
        for (int j = 0; j < 16; ++j) cv[j] = (bf16)fa[j];
        __syncthreads();
        *(bf16x8*)&As[sr][sc] = *(bf16x8*)&cv[0];
        *(bf16x8*)&As[sr][sc + 8] = *(bf16x8*)&cv[8];
        *(bf16x8*)&Bs[sr][sc] = br0;
        *(bf16x8*)&Bs[sr][sc + 8] = br1;
        __syncthreads();
        if (k0 + 32 < HIDDEN) {
#pragma unroll
            for (int j = 0; j < 4; ++j)
                *(float4*)&fa[4 * j] = *(const float4*)(gA + k0 + 32 + 4 * j);
            br0 = *(const bf16x8*)(gB + k0 + 32);
            br1 = *(const bf16x8*)(gB + k0 + 40);
        }

        bf16x8 ah[4], bh[4];
#pragma unroll
        for (int i = 0; i < 4; ++i) {
            ah[i] = *(bf16x8*)&As[wm * 64 + i * 16 + l16][quad * 8];
            bh[i] = *(bf16x8*)&Bs[wn * 64 + i * 16 + l16][quad * 8];
        }
#pragma unroll
        for (int mi = 0; mi < 4; ++mi)
#pragma unroll
            for (int ni = 0; ni < 4; ++ni)
                acc[mi][ni] = __builtin_amdgcn_mfma_f32_16x16x32_bf16(
                    ah[mi], bh[ni], acc[mi][ni], 0, 0, 0);
    }

    const int nb = n0 + wn * 64;
    const int which = nb / HIDDEN;         // 0=Q, 1=K, 2=V
    const int nrel = nb - which * HIDDEN;  // = h*64
    const int h = nrel >> 6;

    if (which < 2) {
        const float scale = (which == 0) ? QSCALE : 1.0f;
        const float* bias = (which == 0) ? bq : bk;
        bf16* dst = (which == 0) ? q_out : k_out;
#pragma unroll
        for (int ni = 0; ni < 4; ++ni) {
            const int dh = ni * 16 + l16;
            const float bb = bias[nrel + dh];
#pragma unroll
            for (int mi = 0; mi < 4; ++mi)
#pragma unroll
                for (int r = 0; r < 4; ++r) {
                    const int m = m0 + wm * 64 + mi * 16 + quad * 4 + r;
                    const int bi = m >> 11, s = m & (SEQ - 1);
                    dst[(((size_t)(bi * NH + h) * SEQ + s) << 6) + dh] =
                        (bf16)(scale * (acc[mi][ni][r] + bb));
                }
        }
    } else {
        // V transposed: Vt[b][h][d][s]
        const int bi = m0 >> 11;
        const int sbase = (m0 & (SEQ - 1)) + wm * 64;
#pragma unroll
        for (int ni = 0; ni < 4; ++ni) {
            const int dh = ni * 16 + l16;
            const float bb = bv[nrel + dh];
            bf16* vrow = v_out + ((size_t)(bi * NH + h) * DH + dh) * SEQ;
#pragma unroll
            for (int mi = 0; mi < 4; ++mi) {
                bf16x4 pk = {(bf16)(acc[mi][ni][0] + bb),
                             (bf16)(acc[mi][ni][1] + bb),
                             (bf16)(acc[mi][ni][2] + bb),
                             (bf16)(acc[mi][ni][3] + bb)};
                *(bf16x4*)(vrow + sbase + mi * 16 + quad * 4) = pk;
            }
        }
    }
}

// ---------------------------------------------------------------------------
// MFMA flash attention. Grid (SEQ/128, NH, BATCH), 4 waves; wave w owns
// queries w*32..+31 (2 groups of 16). S^T = K.Q^T, O^T = V^T.P^T.
// K fragments are loaded DIRECTLY from global (coalesced 16 rows x 64 B,
// L1/L2-resident; identical bytes to the former Ks LDS path). V staged in
// LDS with register prefetch. Softmax: exp2 (log2e folded into Q scale),
// no max-shift (|s|<<126), lane-partial sums reduced once at the end.
// ---------------------------------------------------------------------------
__global__ __launch_bounds__(256) void attn_mfma(const bf16* __restrict__ Q,
                                                 const bf16* __restrict__ K,
                                                 const bf16* __restrict__ Vt,
                                                 const float* __restrict__ mask,
                                                 float* __restrict__ ctx) {
    __shared__ bf16 Vts[64][72];
    __shared__ bf16 Ps[128][72];
    __shared__ int allones_s;

    const int tid = threadIdx.x;
    const int ln = tid & 63, w = tid >> 6;
    const int quad = ln >> 4, l16 = ln & 15;
    const int qt = blockIdx.x, h = blockIdx.y, b = blockIdx.z;
    const size_t bh = (size_t)b * NH + h;
    const bf16* Qp = Q + ((bh * SEQ + (size_t)qt * 128) << 6);
    const bf16* Kp = K + (bh * SEQ << 6);
    const bf16* Vp = Vt + (bh * DH) * SEQ;
    const float* mrow = mask + (size_t)b * SEQ;

    // block-uniform all-ones mask flag (benign race: writers only store 0)
    if (tid == 0) allones_s = 1;
    {
        float4 m0 = *(const float4*)(mrow + tid * 8);
        float4 m1 = *(const float4*)(mrow + tid * 8 + 4);
        bool ok = (m0.x == 1.f) & (m0.y == 1.f) & (m0.z == 1.f) &
                  (m0.w == 1.f) & (m1.x == 1.f) & (m1.y == 1.f) &
                  (m1.z == 1.f) & (m1.w == 1.f);
        __syncthreads();
        if (!ok) allones_s = 0;
    }
    __syncthreads();
    const bool fastmask = (allones_s != 0);

    // Q frags (B-operand of S^T)
    bf16x8 qb[2][2];
#pragma unroll
    for (int qg = 0; qg < 2; ++qg)
#pragma unroll
        for (int hf = 0; hf < 2; ++hf)
            qb[qg][hf] = *(const bf16x8*)(Qp + ((w * 32 + qg * 16 + l16) << 6) +
                                          hf * 32 + quad * 8);
    float mq[2];
#pragma unroll
    for (int qg = 0; qg < 2; ++qg)
        mq[qg] = mrow[qt * 128 + w * 32 + qg * 16 + l16];

    float l_i[2] = {0.f, 0.f};
    f32x4 acc[4][2];
#pragma unroll
    for (int fd = 0; fd < 4; ++fd)
#pragma unroll
        for (int qg = 0; qg < 2; ++qg) acc[fd][qg] = (f32x4){0.f, 0.f, 0.f, 0.f};

    const int sr = tid >> 2, sc = (tid & 3) << 4;
    const bf16* vbase = Vp + (size_t)sr * SEQ + sc;

    bf16x8 vr0 = *(const bf16x8*)vbase;
    bf16x8 vr1 = *(const bf16x8*)(vbase + 8);

    for (int kt = 0; kt < SEQ / 64; ++kt) {
        __syncthreads();  // readers of tile kt-1 done
        *(bf16x8*)&Vts[sr][sc] = vr0;
        *(bf16x8*)&Vts[sr][sc + 8] = vr1;
        __syncthreads();
        if (kt + 1 < SEQ / 64) {
            vr0 = *(const bf16x8*)(vbase + (kt + 1) * 64);
            vr1 = *(const bf16x8*)(vbase + (kt + 1) * 64 + 8);
        }

        // S^T = K.Q^T, K frags direct from global (L1-resident)
        f32x4 st[4][2];
#pragma unroll
        for (int f = 0; f < 4; ++f) {
            const bf16* krow = Kp + (((size_t)kt * 64 + f * 16 + l16) << 6);
            bf16x8 ka0 = *(const bf16x8*)(krow + quad * 8);
            bf16x8 ka1 = *(const bf16x8*)(krow + 32 + quad * 8);
#pragma unroll
            for (int qg = 0; qg < 2; ++qg) {
                f32x4 c = {0.f, 0.f, 0.f, 0.f};
                c = __builtin_amdgcn_mfma_f32_16x16x32_bf16(ka0, qb[qg][0], c, 0, 0, 0);
                c = __builtin_amdgcn_mfma_f32_16x16x32_bf16(ka1, qb[qg][1], c, 0, 0, 0);
                st[f][qg] = c;
            }
        }

        if (!fastmask) {
#pragma unroll
            for (int f = 0; f < 4; ++f) {
                const float4 mk4 = *(const float4*)(mrow + kt * 64 + f * 16 + quad * 4);
                const float mkk[4] = {mk4.x, mk4.y, mk4.z, mk4.w};
#pragma unroll
                for (int qg = 0; qg < 2; ++qg)
#pragma unroll
                    for (int r = 0; r < 4; ++r) {
                        const float ext = mq[qg] * mkk[r];
                        st[f][qg][r] = ext * st[f][qg][r] - (1.0f - ext) * 1e9f;
                    }
            }
        }

        // exp2 (scale pre-folded), lane-partial sums, pack P
#pragma unroll
        for (int qg = 0; qg < 2; ++qg) {
#pragma unroll
            for (int f = 0; f < 4; ++f) {
                float p0 = exp2f(st[f][qg][0]);
                float p1 = exp2f(st[f][qg][1]);
                float p2 = exp2f(st[f][qg][2]);
                float p3 = exp2f(st[f][qg][3]);
                l_i[qg] += (p0 + p1) + (p2 + p3);
                bf16x4 pk = {(bf16)p0, (bf16)p1, (bf16)p2, (bf16)p3};
                *(bf16x4*)&Ps[w * 32 + qg * 16 + l16][f * 16 + quad * 4] = pk;
            }
        }

        // O^T += V^T.P^T (Ps rows wave-local: no barrier)
        bf16x8 pb[2][2];
#pragma unroll
        for (int qg = 0; qg < 2; ++qg)
#pragma unroll
            for (int hf = 0; hf < 2; ++hf)
                pb[qg][hf] =
                    *(bf16x8*)&Ps[w * 32 + qg * 16 + l16][hf * 32 + quad * 8];
#pragma unroll
        for (int fd = 0; fd < 4; ++fd) {
            bf16x8 va0 = *(bf16x8*)&Vts[fd * 16 + l16][quad * 8];
            bf16x8 va1 = *(bf16x8*)&Vts[fd * 16 + l16][32 + quad * 8];
#pragma unroll
            for (int qg = 0; qg < 2; ++qg) {
                f32x4 c = acc[fd][qg];
                c = __builtin_amdgcn_mfma_f32_16x16x32_bf16(va0, pb[qg][0], c, 0, 0, 0);
                c = __builtin_amdgcn_mfma_f32_16x16x32_bf16(va1, pb[qg][1], c, 0, 0, 0);
                acc[fd][qg] = c;
            }
        }
    }

    // final row-sum reduction across quads (query id = l16 only)
#pragma unroll
    for (int qg = 0; qg < 2; ++qg) {
        l_i[qg] += __shfl_xor(l_i[qg], 16);
        l_i[qg] += __shfl_xor(l_i[qg], 32);
    }

    // epilogue: ctx fp32 [B*S][768]
#pragma unroll
    for (int qg = 0; qg < 2; ++qg) {
        const float inv = 1.0f / l_i[qg];
        const size_t row = (size_t)b * SEQ + qt * 128 + w * 32 + qg * 16 + l16;
#pragma unroll
        for (int fd = 0; fd < 4; ++fd) {
            float4 o = {acc[fd][qg][0] * inv, acc[fd][qg][1] * inv,
                        acc[fd][qg][2] * inv, acc[fd][qg][3] * inv};
            *(float4*)(ctx + row * HIDDEN + h * 64 + fd * 16 + quad * 4) = o;
        }
    }
}

// ---------------------------------------------------------------------------
// Output GEMM, 3-term split, 128m x 64n tile, register prefetch.
// A = ctx fp32 (hi/lo split during staging), B = Wot hi/lo.
// Epilogue: +bo, exact erf GELU, fp32 out.
// ---------------------------------------------------------------------------
__global__ __launch_bounds__(256) void gemm_out(const float* __restrict__ ctx,
                                                const bf16* __restrict__ Bhi,
                                                const bf16* __restrict__ Blo,
                                                const float* __restrict__ bo,
                                                float* __restrict__ fout) {
    __shared__ bf16 As_hi[128][40];
    __shared__ bf16 As_lo[128][40];
    __shared__ bf16 Bs_hi[64][40];
    __shared__ bf16 Bs_lo[64][40];

    const int tid = threadIdx.x;
    const int ln = tid & 63, wv = tid >> 6;
    const int quad = ln >> 4, l16 = ln & 15;
    const int wm = wv >> 1, wn = wv & 1;
    const int n0 = blockIdx.x * 64, m0 = blockIdx.y * 128;

    f32x4 acc[4][2];
#pragma unroll
    for (int i = 0; i < 4; ++i)
#pragma unroll
        for (int j = 0; j < 2; ++j) acc[i][j] = (f32x4){0.f, 0.f, 0.f, 0.f};

    const int sra = tid >> 1, sca = (tid & 1) << 4;
    const int srb = tid >> 2, scb = (tid & 3) << 3;
    const float* gA = ctx + (size_t)(m0 + sra) * HIDDEN + sca;
    const bf16* gBh = Bhi + (size_t)(n0 + srb) * HIDDEN + scb;
    const bf16* gBl = Blo + (size_t)(n0 + srb) * HIDDEN + scb;

    float fa[16];
    bf16x8 brh, brl;
#pragma unroll
    for (int j = 0; j < 4; ++j) *(float4*)&fa[4 * j] = *(const float4*)(gA + 4 * j);
    brh = *(const bf16x8*)gBh;
    brl = *(const bf16x8*)gBl;

    for (int k0 = 0; k0 < HIDDEN; k0 += 32) {
        bf16 hi[16], lo[16];
#pragma unroll
        for (int j = 0; j < 16; ++j) {
            hi[j] = (bf16)fa[j];
            lo[j] = (bf16)(fa[j] - (float)hi[j]);
        }
        __syncthreads();
        *(bf16x8*)&As_hi[sra][sca] = *(bf16x8*)&hi[0];
        *(bf16x8*)&As_hi[sra][sca + 8] = *(bf16x8*)&hi[8];
        *(bf16x8*)&As_lo[sra][sca] = *(bf16x8*)&lo[0];
        *(bf16x8*)&As_lo[sra][sca + 8] = *(bf16x8*)&lo[8];
        *(bf16x8*)&Bs_hi[srb][scb] = brh;
        *(bf16x8*)&Bs_lo[srb][scb] = brl;
        __syncthreads();
        if (k0 + 32 < HIDDEN) {
#pragma unroll
            for (int j = 0; j < 4; ++j)
                *(float4*)&fa[4 * j] = *(const float4*)(gA + k0 + 32 + 4 * j);
            brh = *(const bf16x8*)(gBh + k0 + 32);
            brl = *(const bf16x8*)(gBl + k0 + 32);
        }

        bf16x8 ah[4], al[4], bh[2], bl[2];
#pragma unroll
        for (int i = 0; i < 4; ++i) {
            ah[i] = *(bf16x8*)&As_hi[wm * 64 + i * 16 + l16][quad * 8];
            al[i] = *(bf16x8*)&As_lo[wm * 64 + i * 16 + l16][quad * 8];
        }
#pragma unroll
        for (int i = 0; i < 2; ++i) {
            bh[i] = *(bf16x8*)&Bs_hi[wn * 32 + i * 16 + l16][quad * 8];
            bl[i] = *(bf16x8*)&Bs_lo[wn * 32 + i * 16 + l16][quad * 8];
        }
#pragma unroll
        for (int mi = 0; mi < 4; ++mi)
#pragma unroll
            for (int ni = 0; ni < 2; ++ni) {
                f32x4 c = acc[mi][ni];
                c = __builtin_amdgcn_mfma_f32_16x16x32_bf16(ah[mi], bh[ni], c, 0, 0, 0);
                c = __builtin_amdgcn_mfma_f32_16x16x32_bf16(ah[mi], bl[ni], c, 0, 0, 0);
                c = __builtin_amdgcn_mfma_f32_16x16x32_bf16(al[mi], bh[ni], c, 0, 0, 0);
                acc[mi][ni] = c;
            }
    }

#pragma unroll
    for (int ni = 0; ni < 2; ++ni) {
        const int n = n0 + wn * 32 + ni * 16 + l16;
        const float bb = bo[n];
#pragma unroll
        for (int mi = 0; mi < 4; ++mi)
#pragma unroll
            for (int r = 0; r < 4; ++r) {
                const int m = m0 + wm * 64 + mi * 16 + quad * 4 + r;
                float x = acc[mi][ni][r] + bb;
                x = 0.5f * x * (1.0f + erff(x * 0.70710678118654752440f));
                fout[(size_t)m * HIDDEN + n] = x;
            }
    }
}

// ---------------------------------------------------------------------------
extern "C" void kernel_launch(void* const* d_in, const int* in_sizes, int n_in,
                              void* d_out, int out_size, void* d_ws, size_t ws_size,
                              hipStream_t stream) {
    const float* X    = (const float*)d_in[0];
    const float* mask = (const float*)d_in[1];
    const float* Wq   = (const float*)d_in[2];
    const float* bq   = (const float*)d_in[3];
    const float* Wk   = (const float*)d_in[4];
    const float* bk   = (const float*)d_in[5];
    const float* Wv   = (const float*)d_in[6];
    const float* bv   = (const float*)d_in[7];
    const float* Wo   = (const float*)d_in[8];
    const float* bo   = (const float*)d_in[9];
    float* out = (float*)d_out;

    char* w = (char*)d_ws;
    const size_t NE = (size_t)BATCH * SEQ * HIDDEN;  // 6.29M elems
    bf16* q_ws   = (bf16*)w;  w += NE * 2;
    bf16* k_ws   = (bf16*)w;  w += NE * 2;
    bf16* vt_ws  = (bf16*)w;  w += NE * 2;
    float* ctx   = (float*)w; w += NE * 4;
    bf16* Wt     = (bf16*)w;  w += (size_t)3 * HIDDEN * HIDDEN * 2;
    bf16* Wot_hi = (bf16*)w;  w += (size_t)HIDDEN * HIDDEN * 2;
    bf16* Wot_lo = (bf16*)w;  w += (size_t)HIDDEN * HIDDEN * 2;

    prep_w<<<dim3(12, 12, 4), 256, 0, stream>>>(Wq, Wk, Wv, Wo, Wt, Wot_hi,
                                                Wot_lo);
    gemm_qkv<<<dim3(18, 64), 256, 0, stream>>>(X, Wt, bq, bk, bv, q_ws, k_ws,
                                               vt_ws);
    attn_mfma<<<dim3(SEQ / 128, NH, BATCH), 256, 0, stream>>>(q_ws, k_ws, vt_ws,
                                                              mask, ctx);
    gemm_out<<<dim3(12, 64), 256, 0, stream>>>(ctx, Wot_hi, Wot_lo, bo, out);
}

// Round 7
// 301.778 us; speedup vs baseline: 1.3013x; 1.3013x over previous
//
#include <hip/hip_runtime.h>
#include <math.h>

#define HIDDEN 768
#define NH 12
#define DH 64
#define SEQ 2048
#define BATCH 4

typedef __bf16 bf16;
typedef bf16 bf16x4 __attribute__((ext_vector_type(4)));
typedef bf16 bf16x8 __attribute__((ext_vector_type(8)));
typedef float f32x4 __attribute__((ext_vector_type(4)));

// Q pre-scale: 1/sqrt(64) * log2(e), so softmax is exp2(s) directly.
#define QSCALE 0.18033688011112042f

// ---------------------------------------------------------------------------
// prep_x: X fp32 -> Xb bf16 (8 elems/thread)
// ---------------------------------------------------------------------------
__global__ __launch_bounds__(256) void prep_x(const float* __restrict__ X,
                                              bf16* __restrict__ Xb) {
    const size_t i = ((size_t)blockIdx.x * 256 + threadIdx.x) * 8;
    float4 a = *(const float4*)(X + i);
    float4 b = *(const float4*)(X + i + 4);
    bf16x8 o = {(bf16)a.x, (bf16)a.y, (bf16)a.z, (bf16)a.w,
                (bf16)b.x, (bf16)b.y, (bf16)b.z, (bf16)b.w};
    *(bf16x8*)(Xb + i) = o;
}

// ---------------------------------------------------------------------------
// prep_w: transpose weights. z<3: Wq/Wk/Wv -> Wt bf16 [2304][768] (1-term).
// z==3: Wo -> Wot hi/lo bf16 [768][768].
// ---------------------------------------------------------------------------
__global__ __launch_bounds__(256) void prep_w(const float* __restrict__ Wq,
                                              const float* __restrict__ Wk,
                                              const float* __restrict__ Wv,
                                              const float* __restrict__ Wo,
                                              bf16* __restrict__ Wt,
                                              bf16* __restrict__ Wot_hi,
                                              bf16* __restrict__ Wot_lo) {
    __shared__ float Ts[64][68];
    const int tid = threadIdx.x;
    const int n0 = blockIdx.x * 64, k0 = blockIdx.y * 64, z = blockIdx.z;
    const float* W = (z == 0) ? Wq : (z == 1) ? Wk : (z == 2) ? Wv : Wo;

    {
        const int r = tid >> 2, c = (tid & 3) << 4;
        const float* src = W + (size_t)(k0 + r) * HIDDEN + n0 + c;
#pragma unroll
        for (int j = 0; j < 4; ++j)
            *(float4*)&Ts[r][c + 4 * j] = *(const float4*)(src + 4 * j);
    }
    __syncthreads();

    const int nl = tid >> 2, kc = (tid & 3) << 4;
    float v[16];
#pragma unroll
    for (int j = 0; j < 16; ++j) v[j] = Ts[kc + j][nl];

    if (z < 3) {
        bf16 hi[16];
#pragma unroll
        for (int j = 0; j < 16; ++j) hi[j] = (bf16)v[j];
        const size_t off = (size_t)(z * HIDDEN + n0 + nl) * HIDDEN + k0 + kc;
        *(bf16x8*)(Wt + off) = *(bf16x8*)&hi[0];
        *(bf16x8*)(Wt + off + 8) = *(bf16x8*)&hi[8];
    } else {
        bf16 hi[16], lo[16];
#pragma unroll
        for (int j = 0; j < 16; ++j) {
            hi[j] = (bf16)v[j];
            lo[j] = (bf16)(v[j] - (float)hi[j]);
        }
        const size_t off = (size_t)(n0 + nl) * HIDDEN + k0 + kc;
        *(bf16x8*)(Wot_hi + off) = *(bf16x8*)&hi[0];
        *(bf16x8*)(Wot_hi + off + 8) = *(bf16x8*)&hi[8];
        *(bf16x8*)(Wot_lo + off) = *(bf16x8*)&lo[0];
        *(bf16x8*)(Wot_lo + off + 8) = *(bf16x8*)&lo[8];
    }
}

// ---------------------------------------------------------------------------
// QKV GEMM, 1-term bf16, register-prefetch double buffer. 128x128 tile.
// MFMA 16x16x32 layouts (HW-verified R1-R5):
//   A: lane=A[m=l16][k=quad*8+j]; B: lane=B[k=quad*8+j][n=l16];
//   C/D: lane=D[row=quad*4+reg][col=l16]
// ---------------------------------------------------------------------------
__global__ __launch_bounds__(256) void gemm_qkv(
    const bf16* __restrict__ Xb, const bf16* __restrict__ Wt,
    const float* __restrict__ bq, const float* __restrict__ bk,
    const float* __restrict__ bv, bf16* __restrict__ q_out,
    bf16* __restrict__ k_out, bf16* __restrict__ v_out) {
    __shared__ bf16 As[128][40];
    __shared__ bf16 Bs[128][40];

    const int tid = threadIdx.x;
    const int ln = tid & 63, wv = tid >> 6;
    const int quad = ln >> 4, l16 = ln & 15;
    const int wm = wv >> 1, wn = wv & 1;
    const int n0 = blockIdx.x * 128, m0 = blockIdx.y * 128;

    f32x4 acc[4][4];
#pragma unroll
    for (int i = 0; i < 4; ++i)
#pragma unroll
        for (int j = 0; j < 4; ++j) acc[i][j] = (f32x4){0.f, 0.f, 0.f, 0.f};

    const int sr = tid >> 1, sc = (tid & 1) << 4;
    const bf16* gA = Xb + (size_t)(m0 + sr) * HIDDEN + sc;
    const bf16* gB = Wt + (size_t)(n0 + sr) * HIDDEN + sc;

    bf16x8 ar0, ar1, br0, br1;
    ar0 = *(const bf16x8*)gA;
    ar1 = *(const bf16x8*)(gA + 8);
    br0 = *(const bf16x8*)gB;
    br1 = *(const bf16x8*)(gB + 8);

    for (int k0 = 0; k0 < HIDDEN; k0 += 32) {
        __syncthreads();
        *(bf16x8*)&As[sr][sc] = ar0;
        *(bf16x8*)&As[sr][sc + 8] = ar1;
        *(bf16x8*)&Bs[sr][sc] = br0;
        *(bf16x8*)&Bs[sr][sc + 8] = br1;
        __syncthreads();
        if (k0 + 32 < HIDDEN) {
            ar0 = *(const bf16x8*)(gA + k0 + 32);
            ar1 = *(const bf16x8*)(gA + k0 + 40);
            br0 = *(const bf16x8*)(gB + k0 + 32);
            br1 = *(const bf16x8*)(gB + k0 + 40);
        }

        bf16x8 ah[4], bh[4];
#pragma unroll
        for (int i = 0; i < 4; ++i) {
            ah[i] = *(bf16x8*)&As[wm * 64 + i * 16 + l16][quad * 8];
            bh[i] = *(bf16x8*)&Bs[wn * 64 + i * 16 + l16][quad * 8];
        }
#pragma unroll
        for (int mi = 0; mi < 4; ++mi)
#pragma unroll
            for (int ni = 0; ni < 4; ++ni)
                acc[mi][ni] = __builtin_amdgcn_mfma_f32_16x16x32_bf16(
                    ah[mi], bh[ni], acc[mi][ni], 0, 0, 0);
    }

    const int nb = n0 + wn * 64;
    const int which = nb / HIDDEN;         // 0=Q, 1=K, 2=V
    const int nrel = nb - which * HIDDEN;  // = h*64
    const int h = nrel >> 6;

    if (which < 2) {
        const float scale = (which == 0) ? QSCALE : 1.0f;
        const float* bias = (which == 0) ? bq : bk;
        bf16* dst = (which == 0) ? q_out : k_out;
#pragma unroll
        for (int ni = 0; ni < 4; ++ni) {
            const int dh = ni * 16 + l16;
            const float bb = bias[nrel + dh];
#pragma unroll
            for (int mi = 0; mi < 4; ++mi)
#pragma unroll
                for (int r = 0; r < 4; ++r) {
                    const int m = m0 + wm * 64 + mi * 16 + quad * 4 + r;
                    const int bi = m >> 11, s = m & (SEQ - 1);
                    dst[(((size_t)(bi * NH + h) * SEQ + s) << 6) + dh] =
                        (bf16)(scale * (acc[mi][ni][r] + bb));
                }
        }
    } else {
        // V transposed: Vt[b][h][d][s]
        const int bi = m0 >> 11;
        const int sbase = (m0 & (SEQ - 1)) + wm * 64;
#pragma unroll
        for (int ni = 0; ni < 4; ++ni) {
            const int dh = ni * 16 + l16;
            const float bb = bv[nrel + dh];
            bf16* vrow = v_out + ((size_t)(bi * NH + h) * DH + dh) * SEQ;
#pragma unroll
            for (int mi = 0; mi < 4; ++mi) {
                bf16x4 pk = {(bf16)(acc[mi][ni][0] + bb),
                             (bf16)(acc[mi][ni][1] + bb),
                             (bf16)(acc[mi][ni][2] + bb),
                             (bf16)(acc[mi][ni][3] + bb)};
                *(bf16x4*)(vrow + sbase + mi * 16 + quad * 4) = pk;
            }
        }
    }
}

// ---------------------------------------------------------------------------
// MFMA flash attention (R5 structure). Grid (SEQ/128, NH, BATCH), 4 waves;
// wave w owns queries w*32..+31 (2 groups of 16). S^T = K.Q^T, O^T = V^T.P^T.
// K AND V staged in LDS with register prefetch (R6's direct-global K was
// latency-bound: 101 -> 200 us regression; reverted). exp2 softmax, no
// max-shift, lane-partial sums reduced once at the end.
// Epilogue writes ctx as hi/lo bf16 (feeds 3-term out-GEMM with no per-iter
// cvt in its inner loop).
// ---------------------------------------------------------------------------
__global__ __launch_bounds__(256) void attn_mfma(const bf16* __restrict__ Q,
                                                 const bf16* __restrict__ K,
                                                 const bf16* __restrict__ Vt,
                                                 const float* __restrict__ mask,
                                                 bf16* __restrict__ ctx_hi,
                                                 bf16* __restrict__ ctx_lo) {
    __shared__ bf16 Ks[64][72];
    __shared__ bf16 Vts[64][72];
    __shared__ bf16 Ps[128][72];
    __shared__ int allones_s;

    const int tid = threadIdx.x;
    const int ln = tid & 63, w = tid >> 6;
    const int quad = ln >> 4, l16 = ln & 15;
    const int qt = blockIdx.x, h = blockIdx.y, b = blockIdx.z;
    const size_t bh = (size_t)b * NH + h;
    const bf16* Qp = Q + ((bh * SEQ + (size_t)qt * 128) << 6);
    const bf16* Kp = K + (bh * SEQ << 6);
    const bf16* Vp = Vt + (bh * DH) * SEQ;
    const float* mrow = mask + (size_t)b * SEQ;

    // block-uniform all-ones mask flag (benign race: writers only store 0)
    if (tid == 0) allones_s = 1;
    {
        float4 m0 = *(const float4*)(mrow + tid * 8);
        float4 m1 = *(const float4*)(mrow + tid * 8 + 4);
        bool ok = (m0.x == 1.f) & (m0.y == 1.f) & (m0.z == 1.f) &
                  (m0.w == 1.f) & (m1.x == 1.f) & (m1.y == 1.f) &
                  (m1.z == 1.f) & (m1.w == 1.f);
        __syncthreads();
        if (!ok) allones_s = 0;
    }
    __syncthreads();
    const bool fastmask = (allones_s != 0);

    // Q frags (B-operand of S^T)
    bf16x8 qb[2][2];
#pragma unroll
    for (int qg = 0; qg < 2; ++qg)
#pragma unroll
        for (int hf = 0; hf < 2; ++hf)
            qb[qg][hf] = *(const bf16x8*)(Qp + ((w * 32 + qg * 16 + l16) << 6) +
                                          hf * 32 + quad * 8);
    float mq[2];
#pragma unroll
    for (int qg = 0; qg < 2; ++qg)
        mq[qg] = mrow[qt * 128 + w * 32 + qg * 16 + l16];

    float l_i[2] = {0.f, 0.f};
    f32x4 acc[4][2];
#pragma unroll
    for (int fd = 0; fd < 4; ++fd)
#pragma unroll
        for (int qg = 0; qg < 2; ++qg) acc[fd][qg] = (f32x4){0.f, 0.f, 0.f, 0.f};

    const int sr = tid >> 2, sc = (tid & 3) << 4;
    const bf16* kbase = Kp + ((size_t)sr << 6) + sc;
    const bf16* vbase = Vp + (size_t)sr * SEQ + sc;

    bf16x8 kr0, kr1, vr0, vr1;
    kr0 = *(const bf16x8*)kbase;
    kr1 = *(const bf16x8*)(kbase + 8);
    vr0 = *(const bf16x8*)vbase;
    vr1 = *(const bf16x8*)(vbase + 8);

    for (int kt = 0; kt < SEQ / 64; ++kt) {
        __syncthreads();  // readers of tile kt-1 done
        *(bf16x8*)&Ks[sr][sc] = kr0;
        *(bf16x8*)&Ks[sr][sc + 8] = kr1;
        *(bf16x8*)&Vts[sr][sc] = vr0;
        *(bf16x8*)&Vts[sr][sc + 8] = vr1;
        __syncthreads();
        if (kt + 1 < SEQ / 64) {
            kr0 = *(const bf16x8*)(kbase + ((size_t)(kt + 1) << 12));
            kr1 = *(const bf16x8*)(kbase + ((size_t)(kt + 1) << 12) + 8);
            vr0 = *(const bf16x8*)(vbase + (kt + 1) * 64);
            vr1 = *(const bf16x8*)(vbase + (kt + 1) * 64 + 8);
        }

        // S^T = K.Q^T
        f32x4 st[4][2];
#pragma unroll
        for (int f = 0; f < 4; ++f) {
            bf16x8 ka0 = *(bf16x8*)&Ks[f * 16 + l16][quad * 8];
            bf16x8 ka1 = *(bf16x8*)&Ks[f * 16 + l16][32 + quad * 8];
#pragma unroll
            for (int qg = 0; qg < 2; ++qg) {
                f32x4 c = {0.f, 0.f, 0.f, 0.f};
                c = __builtin_amdgcn_mfma_f32_16x16x32_bf16(ka0, qb[qg][0], c, 0, 0, 0);
                c = __builtin_amdgcn_mfma_f32_16x16x32_bf16(ka1, qb[qg][1], c, 0, 0, 0);
                st[f][qg] = c;
            }
        }

        if (!fastmask) {
#pragma unroll
            for (int f = 0; f < 4; ++f) {
                const float4 mk4 = *(const float4*)(mrow + kt * 64 + f * 16 + quad * 4);
                const float mkk[4] = {mk4.x, mk4.y, mk4.z, mk4.w};
#pragma unroll
                for (int qg = 0; qg < 2; ++qg)
#pragma unroll
                    for (int r = 0; r < 4; ++r) {
                        const float ext = mq[qg] * mkk[r];
                        st[f][qg][r] = ext * st[f][qg][r] - (1.0f - ext) * 1e9f;
                    }
            }
        }

        // exp2 (scale pre-folded), lane-partial sums, pack P
#pragma unroll
        for (int qg = 0; qg < 2; ++qg) {
#pragma unroll
            for (int f = 0; f < 4; ++f) {
                float p0 = exp2f(st[f][qg][0]);
                float p1 = exp2f(st[f][qg][1]);
                float p2 = exp2f(st[f][qg][2]);
                float p3 = exp2f(st[f][qg][3]);
                l_i[qg] += (p0 + p1) + (p2 + p3);
                bf16x4 pk = {(bf16)p0, (bf16)p1, (bf16)p2, (bf16)p3};
                *(bf16x4*)&Ps[w * 32 + qg * 16 + l16][f * 16 + quad * 4] = pk;
            }
        }

        // O^T += V^T.P^T (Ps rows wave-local: no barrier)
        bf16x8 pb[2][2];
#pragma unroll
        for (int qg = 0; qg < 2; ++qg)
#pragma unroll
            for (int hf = 0; hf < 2; ++hf)
                pb[qg][hf] =
                    *(bf16x8*)&Ps[w * 32 + qg * 16 + l16][hf * 32 + quad * 8];
#pragma unroll
        for (int fd = 0; fd < 4; ++fd) {
            bf16x8 va0 = *(bf16x8*)&Vts[fd * 16 + l16][quad * 8];
            bf16x8 va1 = *(bf16x8*)&Vts[fd * 16 + l16][32 + quad * 8];
#pragma unroll
            for (int qg = 0; qg < 2; ++qg) {
                f32x4 c = acc[fd][qg];
                c = __builtin_amdgcn_mfma_f32_16x16x32_bf16(va0, pb[qg][0], c, 0, 0, 0);
                c = __builtin_amdgcn_mfma_f32_16x16x32_bf16(va1, pb[qg][1], c, 0, 0, 0);
                acc[fd][qg] = c;
            }
        }
    }

    // final row-sum reduction across quads (query id = l16 only)
#pragma unroll
    for (int qg = 0; qg < 2; ++qg) {
        l_i[qg] += __shfl_xor(l_i[qg], 16);
        l_i[qg] += __shfl_xor(l_i[qg], 32);
    }

    // epilogue: ctx hi/lo bf16, [B*S][768]; lane's 4 d-values contiguous
#pragma unroll
    for (int qg = 0; qg < 2; ++qg) {
        const float inv = 1.0f / l_i[qg];
        const size_t row = (size_t)b * SEQ + qt * 128 + w * 32 + qg * 16 + l16;
#pragma unroll
        for (int fd = 0; fd < 4; ++fd) {
            bf16 hi[4], lo[4];
#pragma unroll
            for (int r = 0; r < 4; ++r) {
                const float val = acc[fd][qg][r] * inv;
                hi[r] = (bf16)val;
                lo[r] = (bf16)(val - (float)hi[r]);
            }
            const size_t idx = row * HIDDEN + h * 64 + fd * 16 + quad * 4;
            *(bf16x4*)(ctx_hi + idx) = *(bf16x4*)&hi[0];
            *(bf16x4*)(ctx_lo + idx) = *(bf16x4*)&lo[0];
        }
    }
}

// ---------------------------------------------------------------------------
// Output GEMM, 3-term split, 128m x 64n tile, register prefetch.
// A = ctx hi/lo bf16 (pre-split by attn epilogue -> staging is plain vector
// copies, no cvt in the K-loop). B = Wot hi/lo.
// Epilogue: +bo, exact erf GELU, fp32 out.
// ---------------------------------------------------------------------------
__global__ __launch_bounds__(256) void gemm_out(const bf16* __restrict__ Ahi,
                                                const bf16* __restrict__ Alo,
                                                const bf16* __restrict__ Bhi,
                                                const bf16* __restrict__ Blo,
                                                const float* __restrict__ bo,
                                                float* __restrict__ fout) {
    __shared__ bf16 As_hi[128][40];
    __shared__ bf16 As_lo[128][40];
    __shared__ bf16 Bs_hi[64][40];
    __shared__ bf16 Bs_lo[64][40];

    const int tid = threadIdx.x;
    const int ln = tid & 63, wv = tid >> 6;
    const int quad = ln >> 4, l16 = ln & 15;
    const int wm = wv >> 1, wn = wv & 1;
    const int n0 = blockIdx.x * 64, m0 = blockIdx.y * 128;

    f32x4 acc[4][2];
#pragma unroll
    for (int i = 0; i < 4; ++i)
#pragma unroll
        for (int j = 0; j < 2; ++j) acc[i][j] = (f32x4){0.f, 0.f, 0.f, 0.f};

    const int sra = tid >> 1, sca = (tid & 1) << 4;  // A: 128 rows x 32 cols
    const int srb = tid >> 2, scb = (tid & 3) << 3;  // B: 64 rows x 32 cols
    const bf16* gAh = Ahi + (size_t)(m0 + sra) * HIDDEN + sca;
    const bf16* gAl = Alo + (size_t)(m0 + sra) * HIDDEN + sca;
    const bf16* gBh = Bhi + (size_t)(n0 + srb) * HIDDEN + scb;
    const bf16* gBl = Blo + (size_t)(n0 + srb) * HIDDEN + scb;

    bf16x8 arh0, arh1, arl0, arl1, brh, brl;
    arh0 = *(const bf16x8*)gAh;
    arh1 = *(const bf16x8*)(gAh + 8);
    arl0 = *(const bf16x8*)gAl;
    arl1 = *(const bf16x8*)(gAl + 8);
    brh = *(const bf16x8*)gBh;
    brl = *(const bf16x8*)gBl;

    for (int k0 = 0; k0 < HIDDEN; k0 += 32) {
        __syncthreads();
        *(bf16x8*)&As_hi[sra][sca] = arh0;
        *(bf16x8*)&As_hi[sra][sca + 8] = arh1;
        *(bf16x8*)&As_lo[sra][sca] = arl0;
        *(bf16x8*)&As_lo[sra][sca + 8] = arl1;
        *(bf16x8*)&Bs_hi[srb][scb] = brh;
        *(bf16x8*)&Bs_lo[srb][scb] = brl;
        __syncthreads();
        if (k0 + 32 < HIDDEN) {
            arh0 = *(const bf16x8*)(gAh + k0 + 32);
            arh1 = *(const bf16x8*)(gAh + k0 + 40);
            arl0 = *(const bf16x8*)(gAl + k0 + 32);
            arl1 = *(const bf16x8*)(gAl + k0 + 40);
            brh = *(const bf16x8*)(gBh + k0 + 32);
            brl = *(const bf16x8*)(gBl + k0 + 32);
        }

        bf16x8 ah[4], al[4], bh[2], bl[2];
#pragma unroll
        for (int i = 0; i < 4; ++i) {
            ah[i] = *(bf16x8*)&As_hi[wm * 64 + i * 16 + l16][quad * 8];
            al[i] = *(bf16x8*)&As_lo[wm * 64 + i * 16 + l16][quad * 8];
        }
#pragma unroll
        for (int i = 0; i < 2; ++i) {
            bh[i] = *(bf16x8*)&Bs_hi[wn * 32 + i * 16 + l16][quad * 8];
            bl[i] = *(bf16x8*)&Bs_lo[wn * 32 + i * 16 + l16][quad * 8];
        }
#pragma unroll
        for (int mi = 0; mi < 4; ++mi)
#pragma unroll
            for (int ni = 0; ni < 2; ++ni) {
                f32x4 c = acc[mi][ni];
                c = __builtin_amdgcn_mfma_f32_16x16x32_bf16(ah[mi], bh[ni], c, 0, 0, 0);
                c = __builtin_amdgcn_mfma_f32_16x16x32_bf16(ah[mi], bl[ni], c, 0, 0, 0);
                c = __builtin_amdgcn_mfma_f32_16x16x32_bf16(al[mi], bh[ni], c, 0, 0, 0);
                acc[mi][ni] = c;
            }
    }

#pragma unroll
    for (int ni = 0; ni < 2; ++ni) {
        const int n = n0 + wn * 32 + ni * 16 + l16;
        const float bb = bo[n];
#pragma unroll
        for (int mi = 0; mi < 4; ++mi)
#pragma unroll
            for (int r = 0; r < 4; ++r) {
                const int m = m0 + wm * 64 + mi * 16 + quad * 4 + r;
                float x = acc[mi][ni][r] + bb;
                x = 0.5f * x * (1.0f + erff(x * 0.70710678118654752440f));
                fout[(size_t)m * HIDDEN + n] = x;
            }
    }
}

// ---------------------------------------------------------------------------
extern "C" void kernel_launch(void* const* d_in, const int* in_sizes, int n_in,
                              void* d_out, int out_size, void* d_ws, size_t ws_size,
                              hipStream_t stream) {
    const float* X    = (const float*)d_in[0];
    const float* mask = (const float*)d_in[1];
    const float* Wq   = (const float*)d_in[2];
    const float* bq   = (const float*)d_in[3];
    const float* Wk   = (const float*)d_in[4];
    const float* bk   = (const float*)d_in[5];
    const float* Wv   = (const float*)d_in[6];
    const float* bv   = (const float*)d_in[7];
    const float* Wo   = (const float*)d_in[8];
    const float* bo   = (const float*)d_in[9];
    float* out = (float*)d_out;

    char* w = (char*)d_ws;
    const size_t NE = (size_t)BATCH * SEQ * HIDDEN;  // 6.29M elems
    bf16* q_ws   = (bf16*)w;  w += NE * 2;
    bf16* k_ws   = (bf16*)w;  w += NE * 2;
    bf16* vt_ws  = (bf16*)w;  w += NE * 2;
    bf16* ctx_hi = (bf16*)w;  w += NE * 2;
    bf16* ctx_lo = (bf16*)w;  w += NE * 2;
    bf16* Xb     = (bf16*)w;  w += NE * 2;
    bf16* Wt     = (bf16*)w;  w += (size_t)3 * HIDDEN * HIDDEN * 2;
    bf16* Wot_hi = (bf16*)w;  w += (size_t)HIDDEN * HIDDEN * 2;
    bf16* Wot_lo = (bf16*)w;  w += (size_t)HIDDEN * HIDDEN * 2;

    prep_x<<<(int)(NE / 2048), 256, 0, stream>>>(X, Xb);
    prep_w<<<dim3(12, 12, 4), 256, 0, stream>>>(Wq, Wk, Wv, Wo, Wt, Wot_hi,
                                                Wot_lo);
    gemm_qkv<<<dim3(18, 64), 256, 0, stream>>>(Xb, Wt, bq, bk, bv, q_ws, k_ws,
                                               vt_ws);
    attn_mfma<<<dim3(SEQ / 128, NH, BATCH), 256, 0, stream>>>(q_ws, k_ws, vt_ws,
                                                              mask, ctx_hi,
                                                              ctx_lo);
    gemm_out<<<dim3(12, 64), 256, 0, stream>>>(ctx_hi, ctx_lo, Wot_hi, Wot_lo,
                                               bo, out);
}

// Round 8
// 286.688 us; speedup vs baseline: 1.3697x; 1.0526x over previous
//
#include <hip/hip_runtime.h>
#include <math.h>

#define HIDDEN 768
#define NH 12
#define DH 64
#define SEQ 2048
#define BATCH 4

typedef __bf16 bf16;
typedef bf16 bf16x4 __attribute__((ext_vector_type(4)));
typedef bf16 bf16x8 __attribute__((ext_vector_type(8)));
typedef float f32x4 __attribute__((ext_vector_type(4)));

// Q pre-scale: 1/sqrt(64) * log2(e), so softmax is exp2(s) directly.
#define QSCALE 0.18033688011112042f

// async global->LDS, 16 B per lane. LDS dest = wave-uniform base + lane*16.
__device__ __forceinline__ void load_lds16(const bf16* g, bf16* l) {
    __builtin_amdgcn_global_load_lds(
        (const __attribute__((address_space(1))) unsigned int*)g,
        (__attribute__((address_space(3))) unsigned int*)l, 16, 0, 0);
}

// ---------------------------------------------------------------------------
// prep_x: X fp32 -> Xb bf16 (8 elems/thread)
// ---------------------------------------------------------------------------
__global__ __launch_bounds__(256) void prep_x(const float* __restrict__ X,
                                              bf16* __restrict__ Xb) {
    const size_t i = ((size_t)blockIdx.x * 256 + threadIdx.x) * 8;
    float4 a = *(const float4*)(X + i);
    float4 b = *(const float4*)(X + i + 4);
    bf16x8 o = {(bf16)a.x, (bf16)a.y, (bf16)a.z, (bf16)a.w,
                (bf16)b.x, (bf16)b.y, (bf16)b.z, (bf16)b.w};
    *(bf16x8*)(Xb + i) = o;
}

// ---------------------------------------------------------------------------
// prep_w: transpose weights. z<3: Wq/Wk/Wv -> Wt bf16 [2304][768] (1-term).
// z==3: Wo -> Wot hi/lo bf16 [768][768].
// ---------------------------------------------------------------------------
__global__ __launch_bounds__(256) void prep_w(const float* __restrict__ Wq,
                                              const float* __restrict__ Wk,
                                              const float* __restrict__ Wv,
                                              const float* __restrict__ Wo,
                                              bf16* __restrict__ Wt,
                                              bf16* __restrict__ Wot_hi,
                                              bf16* __restrict__ Wot_lo) {
    __shared__ float Ts[64][68];
    const int tid = threadIdx.x;
    const int n0 = blockIdx.x * 64, k0 = blockIdx.y * 64, z = blockIdx.z;
    const float* W = (z == 0) ? Wq : (z == 1) ? Wk : (z == 2) ? Wv : Wo;

    {
        const int r = tid >> 2, c = (tid & 3) << 4;
        const float* src = W + (size_t)(k0 + r) * HIDDEN + n0 + c;
#pragma unroll
        for (int j = 0; j < 4; ++j)
            *(float4*)&Ts[r][c + 4 * j] = *(const float4*)(src + 4 * j);
    }
    __syncthreads();

    const int nl = tid >> 2, kc = (tid & 3) << 4;
    float v[16];
#pragma unroll
    for (int j = 0; j < 16; ++j) v[j] = Ts[kc + j][nl];

    if (z < 3) {
        bf16 hi[16];
#pragma unroll
        for (int j = 0; j < 16; ++j) hi[j] = (bf16)v[j];
        const size_t off = (size_t)(z * HIDDEN + n0 + nl) * HIDDEN + k0 + kc;
        *(bf16x8*)(Wt + off) = *(bf16x8*)&hi[0];
        *(bf16x8*)(Wt + off + 8) = *(bf16x8*)&hi[8];
    } else {
        bf16 hi[16], lo[16];
#pragma unroll
        for (int j = 0; j < 16; ++j) {
            hi[j] = (bf16)v[j];
            lo[j] = (bf16)(v[j] - (float)hi[j]);
        }
        const size_t off = (size_t)(n0 + nl) * HIDDEN + k0 + kc;
        *(bf16x8*)(Wot_hi + off) = *(bf16x8*)&hi[0];
        *(bf16x8*)(Wot_hi + off + 8) = *(bf16x8*)&hi[8];
        *(bf16x8*)(Wot_lo + off) = *(bf16x8*)&lo[0];
        *(bf16x8*)(Wot_lo + off + 8) = *(bf16x8*)&lo[8];
    }
}

// ---------------------------------------------------------------------------
// QKV GEMM, 1-term bf16, m97-style global_load_lds staging (width 16),
// UNPADDED LDS [128][32] (64 B rows; frag reads hit the b128 8-cyc floor).
// 128x128 tile, 2-barrier K-loop.
// MFMA 16x16x32 layouts (HW-verified R1-R5):
//   A: lane=A[m=l16][k=quad*8+j]; B: lane=B[k=quad*8+j][n=l16];
//   C/D: lane=D[row=quad*4+reg][col=l16]
// ---------------------------------------------------------------------------
__global__ __launch_bounds__(256) void gemm_qkv(
    const bf16* __restrict__ Xb, const bf16* __restrict__ Wt,
    const float* __restrict__ bq, const float* __restrict__ bk,
    const float* __restrict__ bv, bf16* __restrict__ q_out,
    bf16* __restrict__ k_out, bf16* __restrict__ v_out) {
    __shared__ bf16 As[128][32];
    __shared__ bf16 Bs[128][32];

    const int tid = threadIdx.x;
    const int ln = tid & 63, wv = tid >> 6;
    const int quad = ln >> 4, l16 = ln & 15;
    const int wm = wv >> 1, wn = wv & 1;
    const int n0 = blockIdx.x * 128, m0 = blockIdx.y * 128;

    f32x4 acc[4][4];
#pragma unroll
    for (int i = 0; i < 4; ++i)
#pragma unroll
        for (int j = 0; j < 4; ++j) acc[i][j] = (f32x4){0.f, 0.f, 0.f, 0.f};

    // DMA mapping: thread tid deposits 16 B at flat offset tid*16 (rows 0-63)
    // and 4096+tid*16 (rows 64-127). Global: row m0 + tid/4, col (tid&3)*8.
    const int dr = tid >> 2, dc = (tid & 3) << 3;
    const bf16* gA0 = Xb + (size_t)(m0 + dr) * HIDDEN + dc;
    const bf16* gA1 = Xb + (size_t)(m0 + 64 + dr) * HIDDEN + dc;
    const bf16* gB0 = Wt + (size_t)(n0 + dr) * HIDDEN + dc;
    const bf16* gB1 = Wt + (size_t)(n0 + 64 + dr) * HIDDEN + dc;
    bf16* lA = (bf16*)As + tid * 8;
    bf16* lB = (bf16*)Bs + tid * 8;

    for (int k0 = 0; k0 < HIDDEN; k0 += 32) {
        __syncthreads();  // previous tile's reads complete
        load_lds16(gA0 + k0, lA);
        load_lds16(gA1 + k0, lA + 2048);
        load_lds16(gB0 + k0, lB);
        load_lds16(gB1 + k0, lB + 2048);
        __syncthreads();  // drains vmcnt: DMA data visible

        bf16x8 ah[4], bh[4];
#pragma unroll
        for (int i = 0; i < 4; ++i) {
            ah[i] = *(bf16x8*)&As[wm * 64 + i * 16 + l16][quad * 8];
            bh[i] = *(bf16x8*)&Bs[wn * 64 + i * 16 + l16][quad * 8];
        }
#pragma unroll
        for (int mi = 0; mi < 4; ++mi)
#pragma unroll
            for (int ni = 0; ni < 4; ++ni)
                acc[mi][ni] = __builtin_amdgcn_mfma_f32_16x16x32_bf16(
                    ah[mi], bh[ni], acc[mi][ni], 0, 0, 0);
    }

    const int nb = n0 + wn * 64;
    const int which = nb / HIDDEN;         // 0=Q, 1=K, 2=V
    const int nrel = nb - which * HIDDEN;  // = h*64
    const int h = nrel >> 6;

    if (which < 2) {
        const float scale = (which == 0) ? QSCALE : 1.0f;
        const float* bias = (which == 0) ? bq : bk;
        bf16* dst = (which == 0) ? q_out : k_out;
#pragma unroll
        for (int ni = 0; ni < 4; ++ni) {
            const int dh = ni * 16 + l16;
            const float bb = bias[nrel + dh];
#pragma unroll
            for (int mi = 0; mi < 4; ++mi)
#pragma unroll
                for (int r = 0; r < 4; ++r) {
                    const int m = m0 + wm * 64 + mi * 16 + quad * 4 + r;
                    const int bi = m >> 11, s = m & (SEQ - 1);
                    dst[(((size_t)(bi * NH + h) * SEQ + s) << 6) + dh] =
                        (bf16)(scale * (acc[mi][ni][r] + bb));
                }
        }
    } else {
        // V transposed: Vt[b][h][d][s]
        const int bi = m0 >> 11;
        const int sbase = (m0 & (SEQ - 1)) + wm * 64;
#pragma unroll
        for (int ni = 0; ni < 4; ++ni) {
            const int dh = ni * 16 + l16;
            const float bb = bv[nrel + dh];
            bf16* vrow = v_out + ((size_t)(bi * NH + h) * DH + dh) * SEQ;
#pragma unroll
            for (int mi = 0; mi < 4; ++mi) {
                bf16x4 pk = {(bf16)(acc[mi][ni][0] + bb),
                             (bf16)(acc[mi][ni][1] + bb),
                             (bf16)(acc[mi][ni][2] + bb),
                             (bf16)(acc[mi][ni][3] + bb)};
                *(bf16x4*)(vrow + sbase + mi * 16 + quad * 4) = pk;
            }
        }
    }
}

// ---------------------------------------------------------------------------
// MFMA flash attention — R5 verbatim (measured 101 us). Grid (SEQ/128, NH,
// BATCH), 4 waves; wave w owns queries w*32..+31. S^T = K.Q^T, O^T = V^T.P^T.
// K/V staged in padded LDS with register prefetch; exp2 no-max softmax; Ms
// mask row cached in LDS; ctx written fp32.
// ---------------------------------------------------------------------------
__global__ __launch_bounds__(256) void attn_mfma(const bf16* __restrict__ Q,
                                                 const bf16* __restrict__ K,
                                                 const bf16* __restrict__ Vt,
                                                 const float* __restrict__ mask,
                                                 float* __restrict__ ctx) {
    __shared__ bf16 Ks[64][72];
    __shared__ bf16 Vts[64][72];
    __shared__ bf16 Ps[128][72];
    __shared__ float Ms[SEQ];
    __shared__ int allones_s;

    const int tid = threadIdx.x;
    const int ln = tid & 63, w = tid >> 6;
    const int quad = ln >> 4, l16 = ln & 15;
    const int qt = blockIdx.x, h = blockIdx.y, b = blockIdx.z;
    const size_t bh = (size_t)b * NH + h;
    const bf16* Qp = Q + ((bh * SEQ + (size_t)qt * 128) << 6);
    const bf16* Kp = K + (bh * SEQ << 6);
    const bf16* Vp = Vt + (bh * DH) * SEQ;
    const float* mrow = mask + (size_t)b * SEQ;

    // cache mask row, compute block-uniform all-ones flag
    if (tid == 0) allones_s = 1;
    {
        float4 m0 = *(const float4*)(mrow + tid * 8);
        float4 m1 = *(const float4*)(mrow + tid * 8 + 4);
        *(float4*)&Ms[tid * 8] = m0;
        *(float4*)&Ms[tid * 8 + 4] = m1;
        bool ok = (m0.x == 1.f) & (m0.y == 1.f) & (m0.z == 1.f) &
                  (m0.w == 1.f) & (m1.x == 1.f) & (m1.y == 1.f) &
                  (m1.z == 1.f) & (m1.w == 1.f);
        __syncthreads();
        if (!ok) allones_s = 0;  // benign race: all writers store 0
    }
    __syncthreads();
    const bool fastmask = (allones_s != 0);

    // Q frags (B-operand of S^T)
    bf16x8 qb[2][2];
#pragma unroll
    for (int qg = 0; qg < 2; ++qg)
#pragma unroll
        for (int hf = 0; hf < 2; ++hf)
            qb[qg][hf] = *(const bf16x8*)(Qp + ((w * 32 + qg * 16 + l16) << 6) +
                                          hf * 32 + quad * 8);
    float mq[2];
#pragma unroll
    for (int qg = 0; qg < 2; ++qg)
        mq[qg] = Ms[qt * 128 + w * 32 + qg * 16 + l16];

    float l_i[2] = {0.f, 0.f};
    f32x4 acc[4][2];
#pragma unroll
    for (int fd = 0; fd < 4; ++fd)
#pragma unroll
        for (int qg = 0; qg < 2; ++qg) acc[fd][qg] = (f32x4){0.f, 0.f, 0.f, 0.f};

    const int sr = tid >> 2, sc = (tid & 3) << 4;
    const bf16* kbase = Kp + ((size_t)sr << 6) + sc;
    const bf16* vbase = Vp + (size_t)sr * SEQ + sc;

    bf16x8 kr0, kr1, vr0, vr1;
    kr0 = *(const bf16x8*)kbase;
    kr1 = *(const bf16x8*)(kbase + 8);
    vr0 = *(const bf16x8*)vbase;
    vr1 = *(const bf16x8*)(vbase + 8);

    for (int kt = 0; kt < SEQ / 64; ++kt) {
        __syncthreads();  // readers of tile kt-1 done
        *(bf16x8*)&Ks[sr][sc] = kr0;
        *(bf16x8*)&Ks[sr][sc + 8] = kr1;
        *(bf16x8*)&Vts[sr][sc] = vr0;
        *(bf16x8*)&Vts[sr][sc + 8] = vr1;
        __syncthreads();
        if (kt + 1 < SEQ / 64) {
            kr0 = *(const bf16x8*)(kbase + ((size_t)(kt + 1) << 12));
            kr1 = *(const bf16x8*)(kbase + ((size_t)(kt + 1) << 12) + 8);
            vr0 = *(const bf16x8*)(vbase + (kt + 1) * 64);
            vr1 = *(const bf16x8*)(vbase + (kt + 1) * 64 + 8);
        }

        // S^T = K.Q^T
        f32x4 st[4][2];
#pragma unroll
        for (int f = 0; f < 4; ++f) {
            bf16x8 ka0 = *(bf16x8*)&Ks[f * 16 + l16][quad * 8];
            bf16x8 ka1 = *(bf16x8*)&Ks[f * 16 + l16][32 + quad * 8];
#pragma unroll
            for (int qg = 0; qg < 2; ++qg) {
                f32x4 c = {0.f, 0.f, 0.f, 0.f};
                c = __builtin_amdgcn_mfma_f32_16x16x32_bf16(ka0, qb[qg][0], c, 0, 0, 0);
                c = __builtin_amdgcn_mfma_f32_16x16x32_bf16(ka1, qb[qg][1], c, 0, 0, 0);
                st[f][qg] = c;
            }
        }

        if (!fastmask) {
#pragma unroll
            for (int f = 0; f < 4; ++f) {
                const float4 mk4 = *(const float4*)&Ms[kt * 64 + f * 16 + quad * 4];
                const float mkk[4] = {mk4.x, mk4.y, mk4.z, mk4.w};
#pragma unroll
                for (int qg = 0; qg < 2; ++qg)
#pragma unroll
                    for (int r = 0; r < 4; ++r) {
                        const float ext = mq[qg] * mkk[r];
                        st[f][qg][r] = ext * st[f][qg][r] - (1.0f - ext) * 1e9f;
                    }
            }
        }

        // exp2 (scale pre-folded), lane-partial sums, pack P
#pragma unroll
        for (int qg = 0; qg < 2; ++qg) {
#pragma unroll
            for (int f = 0; f < 4; ++f) {
                float p0 = exp2f(st[f][qg][0]);
                float p1 = exp2f(st[f][qg][1]);
                float p2 = exp2f(st[f][qg][2]);
                float p3 = exp2f(st[f][qg][3]);
                l_i[qg] += (p0 + p1) + (p2 + p3);
                bf16x4 pk = {(bf16)p0, (bf16)p1, (bf16)p2, (bf16)p3};
                *(bf16x4*)&Ps[w * 32 + qg * 16 + l16][f * 16 + quad * 4] = pk;
            }
        }

        // O^T += V^T.P^T (Ps rows wave-local: no barrier)
        bf16x8 pb[2][2];
#pragma unroll
        for (int qg = 0; qg < 2; ++qg)
#pragma unroll
            for (int hf = 0; hf < 2; ++hf)
                pb[qg][hf] =
                    *(bf16x8*)&Ps[w * 32 + qg * 16 + l16][hf * 32 + quad * 8];
#pragma unroll
        for (int fd = 0; fd < 4; ++fd) {
            bf16x8 va0 = *(bf16x8*)&Vts[fd * 16 + l16][quad * 8];
            bf16x8 va1 = *(bf16x8*)&Vts[fd * 16 + l16][32 + quad * 8];
#pragma unroll
            for (int qg = 0; qg < 2; ++qg) {
                f32x4 c = acc[fd][qg];
                c = __builtin_amdgcn_mfma_f32_16x16x32_bf16(va0, pb[qg][0], c, 0, 0, 0);
                c = __builtin_amdgcn_mfma_f32_16x16x32_bf16(va1, pb[qg][1], c, 0, 0, 0);
                acc[fd][qg] = c;
            }
        }
    }

    // final row-sum reduction across quads (query id = l16 only)
#pragma unroll
    for (int qg = 0; qg < 2; ++qg) {
        l_i[qg] += __shfl_xor(l_i[qg], 16);
        l_i[qg] += __shfl_xor(l_i[qg], 32);
    }

    // epilogue: ctx fp32 [B*S][768]
#pragma unroll
    for (int qg = 0; qg < 2; ++qg) {
        const float inv = 1.0f / l_i[qg];
        const size_t row = (size_t)b * SEQ + qt * 128 + w * 32 + qg * 16 + l16;
#pragma unroll
        for (int fd = 0; fd < 4; ++fd) {
            float4 o = {acc[fd][qg][0] * inv, acc[fd][qg][1] * inv,
                        acc[fd][qg][2] * inv, acc[fd][qg][3] * inv};
            *(float4*)(ctx + row * HIDDEN + h * 64 + fd * 16 + quad * 4) = o;
        }
    }
}

// ---------------------------------------------------------------------------
// Output GEMM, 3-term split, 128m x 64n tile. A = ctx fp32, hi/lo split
// during staging (R5 path, register prefetch). B = Wot hi/lo via
// global_load_lds into UNPADDED [64][32] tiles. Epilogue: +bo, erf GELU.
// ---------------------------------------------------------------------------
__global__ __launch_bounds__(256) void gemm_out(const float* __restrict__ ctx,
                                                const bf16* __restrict__ Bhi,
                                                const bf16* __restrict__ Blo,
                                                const float* __restrict__ bo,
                                                float* __restrict__ fout) {
    __shared__ bf16 As_hi[128][40];
    __shared__ bf16 As_lo[128][40];
    __shared__ bf16 Bs_hi[64][32];
    __shared__ bf16 Bs_lo[64][32];

    const int tid = threadIdx.x;
    const int ln = tid & 63, wv = tid >> 6;
    const int quad = ln >> 4, l16 = ln & 15;
    const int wm = wv >> 1, wn = wv & 1;
    const int n0 = blockIdx.x * 64, m0 = blockIdx.y * 128;

    f32x4 acc[4][2];
#pragma unroll
    for (int i = 0; i < 4; ++i)
#pragma unroll
        for (int j = 0; j < 2; ++j) acc[i][j] = (f32x4){0.f, 0.f, 0.f, 0.f};

    const int sra = tid >> 1, sca = (tid & 1) << 4;  // A: 128 rows x 32 cols
    const float* gA = ctx + (size_t)(m0 + sra) * HIDDEN + sca;
    // B DMA: thread tid deposits at flat offset tid*16 -> row tid/4, col (tid&3)*8
    const int drb = tid >> 2, dcb = (tid & 3) << 3;
    const bf16* gBh = Bhi + (size_t)(n0 + drb) * HIDDEN + dcb;
    const bf16* gBl = Blo + (size_t)(n0 + drb) * HIDDEN + dcb;
    bf16* lBh = (bf16*)Bs_hi + tid * 8;
    bf16* lBl = (bf16*)Bs_lo + tid * 8;

    float fa[16];
#pragma unroll
    for (int j = 0; j < 4; ++j) *(float4*)&fa[4 * j] = *(const float4*)(gA + 4 * j);

    for (int k0 = 0; k0 < HIDDEN; k0 += 32) {
        bf16 hi[16], lo[16];
#pragma unroll
        for (int j = 0; j < 16; ++j) {
            hi[j] = (bf16)fa[j];
            lo[j] = (bf16)(fa[j] - (float)hi[j]);
        }
        __syncthreads();  // previous tile's reads complete
        load_lds16(gBh + k0, lBh);
        load_lds16(gBl + k0, lBl);
        *(bf16x8*)&As_hi[sra][sca] = *(bf16x8*)&hi[0];
        *(bf16x8*)&As_hi[sra][sca + 8] = *(bf16x8*)&hi[8];
        *(bf16x8*)&As_lo[sra][sca] = *(bf16x8*)&lo[0];
        *(bf16x8*)&As_lo[sra][sca + 8] = *(bf16x8*)&lo[8];
        __syncthreads();  // drains vmcnt (B DMA) + lgkm (A writes)
        if (k0 + 32 < HIDDEN) {
#pragma unroll
            for (int j = 0; j < 4; ++j)
                *(float4*)&fa[4 * j] = *(const float4*)(gA + k0 + 32 + 4 * j);
        }

        bf16x8 ah[4], al[4], bh[2], bl[2];
#pragma unroll
        for (int i = 0; i < 4; ++i) {
            ah[i] = *(bf16x8*)&As_hi[wm * 64 + i * 16 + l16][quad * 8];
            al[i] = *(bf16x8*)&As_lo[wm * 64 + i * 16 + l16][quad * 8];
        }
#pragma unroll
        for (int i = 0; i < 2; ++i) {
            bh[i] = *(bf16x8*)&Bs_hi[wn * 32 + i * 16 + l16][quad * 8];
            bl[i] = *(bf16x8*)&Bs_lo[wn * 32 + i * 16 + l16][quad * 8];
        }
#pragma unroll
        for (int mi = 0; mi < 4; ++mi)
#pragma unroll
            for (int ni = 0; ni < 2; ++ni) {
                f32x4 c = acc[mi][ni];
                c = __builtin_amdgcn_mfma_f32_16x16x32_bf16(ah[mi], bh[ni], c, 0, 0, 0);
                c = __builtin_amdgcn_mfma_f32_16x16x32_bf16(ah[mi], bl[ni], c, 0, 0, 0);
                c = __builtin_amdgcn_mfma_f32_16x16x32_bf16(al[mi], bh[ni], c, 0, 0, 0);
                acc[mi][ni] = c;
            }
    }

#pragma unroll
    for (int ni = 0; ni < 2; ++ni) {
        const int n = n0 + wn * 32 + ni * 16 + l16;
        const float bb = bo[n];
#pragma unroll
        for (int mi = 0; mi < 4; ++mi)
#pragma unroll
            for (int r = 0; r < 4; ++r) {
                const int m = m0 + wm * 64 + mi * 16 + quad * 4 + r;
                float x = acc[mi][ni][r] + bb;
                x = 0.5f * x * (1.0f + erff(x * 0.70710678118654752440f));
                fout[(size_t)m * HIDDEN + n] = x;
            }
    }
}

// ---------------------------------------------------------------------------
extern "C" void kernel_launch(void* const* d_in, const int* in_sizes, int n_in,
                              void* d_out, int out_size, void* d_ws, size_t ws_size,
                              hipStream_t stream) {
    const float* X    = (const float*)d_in[0];
    const float* mask = (const float*)d_in[1];
    const float* Wq   = (const float*)d_in[2];
    const float* bq   = (const float*)d_in[3];
    const float* Wk   = (const float*)d_in[4];
    const float* bk   = (const float*)d_in[5];
    const float* Wv   = (const float*)d_in[6];
    const float* bv   = (const float*)d_in[7];
    const float* Wo   = (const float*)d_in[8];
    const float* bo   = (const float*)d_in[9];
    float* out = (float*)d_out;

    char* w = (char*)d_ws;
    const size_t NE = (size_t)BATCH * SEQ * HIDDEN;  // 6.29M elems
    bf16* q_ws   = (bf16*)w;  w += NE * 2;
    bf16* k_ws   = (bf16*)w;  w += NE * 2;
    bf16* vt_ws  = (bf16*)w;  w += NE * 2;
    float* ctx   = (float*)w; w += NE * 4;
    bf16* Xb     = (bf16*)w;  w += NE * 2;
    bf16* Wt     = (bf16*)w;  w += (size_t)3 * HIDDEN * HIDDEN * 2;
    bf16* Wot_hi = (bf16*)w;  w += (size_t)HIDDEN * HIDDEN * 2;
    bf16* Wot_lo = (bf16*)w;  w += (size_t)HIDDEN * HIDDEN * 2;

    prep_x<<<(int)(NE / 2048), 256, 0, stream>>>(X, Xb);
    prep_w<<<dim3(12, 12, 4), 256, 0, stream>>>(Wq, Wk, Wv, Wo, Wt, Wot_hi,
                                                Wot_lo);
    gemm_qkv<<<dim3(18, 64), 256, 0, stream>>>(Xb, Wt, bq, bk, bv, q_ws, k_ws,
                                               vt_ws);
    attn_mfma<<<dim3(SEQ / 128, NH, BATCH), 256, 0, stream>>>(q_ws, k_ws, vt_ws,
                                                              mask, ctx);
    gemm_out<<<dim3(12, 64), 256, 0, stream>>>(ctx, Wot_hi, Wot_lo, bo, out);
}

// Round 9
// 281.593 us; speedup vs baseline: 1.3945x; 1.0181x over previous
//
#include <hip/hip_runtime.h>
#include <math.h>

#define HIDDEN 768
#define NH 12
#define DH 64
#define SEQ 2048
#define BATCH 4

typedef __bf16 bf16;
typedef bf16 bf16x4 __attribute__((ext_vector_type(4)));
typedef bf16 bf16x8 __attribute__((ext_vector_type(8)));
typedef float f32x4 __attribute__((ext_vector_type(4)));

// Q pre-scale: 1/sqrt(64). Softmax uses __expf (bare v_exp path; libm exp2f
// lowers to the slower ocml wrapper -- measured +12us in R6-R8).
#define QSCALE 0.125f

// async global->LDS, 16 B per lane. LDS dest = wave-uniform base + lane*16.
__device__ __forceinline__ void load_lds16(const bf16* g, bf16* l) {
    __builtin_amdgcn_global_load_lds(
        (const __attribute__((address_space(1))) unsigned int*)g,
        (__attribute__((address_space(3))) unsigned int*)l, 16, 0, 0);
}

// ---------------------------------------------------------------------------
// prep_x: X fp32 -> Xb bf16 (8 elems/thread)
// ---------------------------------------------------------------------------
__global__ __launch_bounds__(256) void prep_x(const float* __restrict__ X,
                                              bf16* __restrict__ Xb) {
    const size_t i = ((size_t)blockIdx.x * 256 + threadIdx.x) * 8;
    float4 a = *(const float4*)(X + i);
    float4 b = *(const float4*)(X + i + 4);
    bf16x8 o = {(bf16)a.x, (bf16)a.y, (bf16)a.z, (bf16)a.w,
                (bf16)b.x, (bf16)b.y, (bf16)b.z, (bf16)b.w};
    *(bf16x8*)(Xb + i) = o;
}

// ---------------------------------------------------------------------------
// prep_w: transpose weights. z<3: Wq/Wk/Wv -> Wt bf16 [2304][768] (1-term).
// z==3: Wo -> Wot hi/lo bf16 [768][768].
// ---------------------------------------------------------------------------
__global__ __launch_bounds__(256) void prep_w(const float* __restrict__ Wq,
                                              const float* __restrict__ Wk,
                                              const float* __restrict__ Wv,
                                              const float* __restrict__ Wo,
                                              bf16* __restrict__ Wt,
                                              bf16* __restrict__ Wot_hi,
                                              bf16* __restrict__ Wot_lo) {
    __shared__ float Ts[64][68];
    const int tid = threadIdx.x;
    const int n0 = blockIdx.x * 64, k0 = blockIdx.y * 64, z = blockIdx.z;
    const float* W = (z == 0) ? Wq : (z == 1) ? Wk : (z == 2) ? Wv : Wo;

    {
        const int r = tid >> 2, c = (tid & 3) << 4;
        const float* src = W + (size_t)(k0 + r) * HIDDEN + n0 + c;
#pragma unroll
        for (int j = 0; j < 4; ++j)
            *(float4*)&Ts[r][c + 4 * j] = *(const float4*)(src + 4 * j);
    }
    __syncthreads();

    const int nl = tid >> 2, kc = (tid & 3) << 4;
    float v[16];
#pragma unroll
    for (int j = 0; j < 16; ++j) v[j] = Ts[kc + j][nl];

    if (z < 3) {
        bf16 hi[16];
#pragma unroll
        for (int j = 0; j < 16; ++j) hi[j] = (bf16)v[j];
        const size_t off = (size_t)(z * HIDDEN + n0 + nl) * HIDDEN + k0 + kc;
        *(bf16x8*)(Wt + off) = *(bf16x8*)&hi[0];
        *(bf16x8*)(Wt + off + 8) = *(bf16x8*)&hi[8];
    } else {
        bf16 hi[16], lo[16];
#pragma unroll
        for (int j = 0; j < 16; ++j) {
            hi[j] = (bf16)v[j];
            lo[j] = (bf16)(v[j] - (float)hi[j]);
        }
        const size_t off = (size_t)(n0 + nl) * HIDDEN + k0 + kc;
        *(bf16x8*)(Wot_hi + off) = *(bf16x8*)&hi[0];
        *(bf16x8*)(Wot_hi + off + 8) = *(bf16x8*)&hi[8];
        *(bf16x8*)(Wot_lo + off) = *(bf16x8*)&lo[0];
        *(bf16x8*)(Wot_lo + off + 8) = *(bf16x8*)&lo[8];
    }
}

// ---------------------------------------------------------------------------
// QKV GEMM (R8 verbatim): 1-term bf16, global_load_lds staging, unpadded
// [128][32] LDS (64 B rows -> bank-uniform b128 reads). 128x128 tile.
// MFMA 16x16x32 layouts (HW-verified R1-R8):
//   A: lane=A[m=l16][k=quad*8+j]; B: lane=B[k=quad*8+j][n=l16];
//   C/D: lane=D[row=quad*4+reg][col=l16]
// ---------------------------------------------------------------------------
__global__ __launch_bounds__(256) void gemm_qkv(
    const bf16* __restrict__ Xb, const bf16* __restrict__ Wt,
    const float* __restrict__ bq, const float* __restrict__ bk,
    const float* __restrict__ bv, bf16* __restrict__ q_out,
    bf16* __restrict__ k_out, bf16* __restrict__ v_out) {
    __shared__ bf16 As[128][32];
    __shared__ bf16 Bs[128][32];

    const int tid = threadIdx.x;
    const int ln = tid & 63, wv = tid >> 6;
    const int quad = ln >> 4, l16 = ln & 15;
    const int wm = wv >> 1, wn = wv & 1;
    const int n0 = blockIdx.x * 128, m0 = blockIdx.y * 128;

    f32x4 acc[4][4];
#pragma unroll
    for (int i = 0; i < 4; ++i)
#pragma unroll
        for (int j = 0; j < 4; ++j) acc[i][j] = (f32x4){0.f, 0.f, 0.f, 0.f};

    const int dr = tid >> 2, dc = (tid & 3) << 3;
    const bf16* gA0 = Xb + (size_t)(m0 + dr) * HIDDEN + dc;
    const bf16* gA1 = Xb + (size_t)(m0 + 64 + dr) * HIDDEN + dc;
    const bf16* gB0 = Wt + (size_t)(n0 + dr) * HIDDEN + dc;
    const bf16* gB1 = Wt + (size_t)(n0 + 64 + dr) * HIDDEN + dc;
    bf16* lA = (bf16*)As + tid * 8;
    bf16* lB = (bf16*)Bs + tid * 8;

    for (int k0 = 0; k0 < HIDDEN; k0 += 32) {
        __syncthreads();
        load_lds16(gA0 + k0, lA);
        load_lds16(gA1 + k0, lA + 2048);
        load_lds16(gB0 + k0, lB);
        load_lds16(gB1 + k0, lB + 2048);
        __syncthreads();

        bf16x8 ah[4], bh[4];
#pragma unroll
        for (int i = 0; i < 4; ++i) {
            ah[i] = *(bf16x8*)&As[wm * 64 + i * 16 + l16][quad * 8];
            bh[i] = *(bf16x8*)&Bs[wn * 64 + i * 16 + l16][quad * 8];
        }
#pragma unroll
        for (int mi = 0; mi < 4; ++mi)
#pragma unroll
            for (int ni = 0; ni < 4; ++ni)
                acc[mi][ni] = __builtin_amdgcn_mfma_f32_16x16x32_bf16(
                    ah[mi], bh[ni], acc[mi][ni], 0, 0, 0);
    }

    const int nb = n0 + wn * 64;
    const int which = nb / HIDDEN;         // 0=Q, 1=K, 2=V
    const int nrel = nb - which * HIDDEN;  // = h*64
    const int h = nrel >> 6;

    if (which < 2) {
        const float scale = (which == 0) ? QSCALE : 1.0f;
        const float* bias = (which == 0) ? bq : bk;
        bf16* dst = (which == 0) ? q_out : k_out;
#pragma unroll
        for (int ni = 0; ni < 4; ++ni) {
            const int dh = ni * 16 + l16;
            const float bb = bias[nrel + dh];
#pragma unroll
            for (int mi = 0; mi < 4; ++mi)
#pragma unroll
                for (int r = 0; r < 4; ++r) {
                    const int m = m0 + wm * 64 + mi * 16 + quad * 4 + r;
                    const int bi = m >> 11, s = m & (SEQ - 1);
                    dst[(((size_t)(bi * NH + h) * SEQ + s) << 6) + dh] =
                        (bf16)(scale * (acc[mi][ni][r] + bb));
                }
        }
    } else {
        // V transposed: Vt[b][h][d][s]
        const int bi = m0 >> 11;
        const int sbase = (m0 & (SEQ - 1)) + wm * 64;
#pragma unroll
        for (int ni = 0; ni < 4; ++ni) {
            const int dh = ni * 16 + l16;
            const float bb = bv[nrel + dh];
            bf16* vrow = v_out + ((size_t)(bi * NH + h) * DH + dh) * SEQ;
#pragma unroll
            for (int mi = 0; mi < 4; ++mi) {
                bf16x4 pk = {(bf16)(acc[mi][ni][0] + bb),
                             (bf16)(acc[mi][ni][1] + bb),
                             (bf16)(acc[mi][ni][2] + bb),
                             (bf16)(acc[mi][ni][3] + bb)};
                *(bf16x4*)(vrow + sbase + mi * 16 + quad * 4) = pk;
            }
        }
    }
}

// ---------------------------------------------------------------------------
// MFMA flash attention. Grid (SEQ/128, NH, BATCH), 4 waves; wave w owns
// queries w*32..+31. S^T = K.Q^T, O^T = V^T.P^T. __expf no-max softmax
// (R5 path). K/V staged via global_load_lds with XOR-swizzled [64][64]
// tiles (chunk c stored at c ^ (row&7): per-lane source permutation within
// one 128 B line keeps coalescing; LDS reads touch all 32 banks) and
// DOUBLE BUFFER: DMA for tile kt+1 issued right after the single per-tile
// barrier, drained by the next barrier -> latency hidden, 1 barrier/tile,
// no staging VGPRs or ds_writes.
// ---------------------------------------------------------------------------
__global__ __launch_bounds__(256) void attn_mfma(const bf16* __restrict__ Q,
                                                 const bf16* __restrict__ K,
                                                 const bf16* __restrict__ Vt,
                                                 const float* __restrict__ mask,
                                                 float* __restrict__ ctx) {
    __shared__ bf16 Ks[2][64][64];   // xor-swizzled
    __shared__ bf16 Vts[2][64][64];  // xor-swizzled
    __shared__ bf16 Ps[128][72];
    __shared__ int allones_s;

    const int tid = threadIdx.x;
    const int ln = tid & 63, w = tid >> 6;
    const int quad = ln >> 4, l16 = ln & 15;
    const int qt = blockIdx.x, h = blockIdx.y, b = blockIdx.z;
    const size_t bh = (size_t)b * NH + h;
    const bf16* Qp = Q + ((bh * SEQ + (size_t)qt * 128) << 6);
    const bf16* Kp = K + (bh * SEQ << 6);
    const bf16* Vp = Vt + (bh * DH) * SEQ;
    const float* mrow = mask + (size_t)b * SEQ;

    // block-uniform all-ones mask flag (benign race: writers only store 0)
    if (tid == 0) allones_s = 1;
    {
        float4 m0 = *(const float4*)(mrow + tid * 8);
        float4 m1 = *(const float4*)(mrow + tid * 8 + 4);
        bool ok = (m0.x == 1.f) & (m0.y == 1.f) & (m0.z == 1.f) &
                  (m0.w == 1.f) & (m1.x == 1.f) & (m1.y == 1.f) &
                  (m1.z == 1.f) & (m1.w == 1.f);
        __syncthreads();
        if (!ok) allones_s = 0;
    }

    // DMA lane mapping: per wave-instr q, lane covers row rl, 16B-chunk ln&7;
    // source chunk is xor-swizzled.
    const int rl0 = (w * 2 + 0) * 8 + (ln >> 3);
    const int rl1 = (w * 2 + 1) * 8 + (ln >> 3);
    const int sch = ((ln & 7) ^ (ln >> 3)) << 3;  // source col in elems
    bf16* ldK0 = &Ks[0][0][0] + (w * 2 + 0) * 512 + ln * 8;
    bf16* ldK1 = &Ks[0][0][0] + (w * 2 + 1) * 512 + ln * 8;
    bf16* ldV0 = &Vts[0][0][0] + (w * 2 + 0) * 512 + ln * 8;
    bf16* ldV1 = &Vts[0][0][0] + (w * 2 + 1) * 512 + ln * 8;
    const bf16* gK0 = Kp + ((size_t)rl0 << 6) + sch;
    const bf16* gK1 = Kp + ((size_t)rl1 << 6) + sch;
    const bf16* gV0 = Vp + (size_t)rl0 * SEQ + sch;
    const bf16* gV1 = Vp + (size_t)rl1 * SEQ + sch;

    // Q frags (B-operand of S^T)
    bf16x8 qb[2][2];
#pragma unroll
    for (int qg = 0; qg < 2; ++qg)
#pragma unroll
        for (int hf = 0; hf < 2; ++hf)
            qb[qg][hf] = *(const bf16x8*)(Qp + ((w * 32 + qg * 16 + l16) << 6) +
                                          hf * 32 + quad * 8);
    float mq[2];
#pragma unroll
    for (int qg = 0; qg < 2; ++qg)
        mq[qg] = mrow[qt * 128 + w * 32 + qg * 16 + l16];

    float l_i[2] = {0.f, 0.f};
    f32x4 acc[4][2];
#pragma unroll
    for (int fd = 0; fd < 4; ++fd)
#pragma unroll
        for (int qg = 0; qg < 2; ++qg) acc[fd][qg] = (f32x4){0.f, 0.f, 0.f, 0.f};

    // prologue: DMA tile 0 into buffer 0
    load_lds16(gK0, ldK0);
    load_lds16(gK1, ldK1);
    load_lds16(gV0, ldV0);
    load_lds16(gV1, ldV1);

    const int swz = (l16 & 7);  // read-side xor key (row & 7)

    for (int kt = 0; kt < SEQ / 64; ++kt) {
        const int cur = kt & 1;
        __syncthreads();  // drains DMA for tile kt; orders prev-tile reads
        const bool fastmask = (allones_s != 0);
        if (kt + 1 < SEQ / 64) {
            const int nb = (cur ^ 1) * 4096;
            load_lds16(gK0 + ((size_t)(kt + 1) << 12), ldK0 + nb);
            load_lds16(gK1 + ((size_t)(kt + 1) << 12), ldK1 + nb);
            load_lds16(gV0 + (kt + 1) * 64, ldV0 + nb);
            load_lds16(gV1 + (kt + 1) * 64, ldV1 + nb);
        }

        // S^T = K.Q^T (swizzled frag reads: chunk (h*4+quad) ^ (row&7))
        f32x4 st[4][2];
#pragma unroll
        for (int f = 0; f < 4; ++f) {
            const bf16* krow = &Ks[cur][f * 16 + l16][0];
            bf16x8 ka0 = *(const bf16x8*)(krow + ((quad ^ swz) << 3));
            bf16x8 ka1 = *(const bf16x8*)(krow + (((4 + quad) ^ swz) << 3));
#pragma unroll
            for (int qg = 0; qg < 2; ++qg) {
                f32x4 c = {0.f, 0.f, 0.f, 0.f};
                c = __builtin_amdgcn_mfma_f32_16x16x32_bf16(ka0, qb[qg][0], c, 0, 0, 0);
                c = __builtin_amdgcn_mfma_f32_16x16x32_bf16(ka1, qb[qg][1], c, 0, 0, 0);
                st[f][qg] = c;
            }
        }

        if (!fastmask) {
#pragma unroll
            for (int f = 0; f < 4; ++f) {
                const float4 mk4 = *(const float4*)(mrow + kt * 64 + f * 16 + quad * 4);
                const float mkk[4] = {mk4.x, mk4.y, mk4.z, mk4.w};
#pragma unroll
                for (int qg = 0; qg < 2; ++qg)
#pragma unroll
                    for (int r = 0; r < 4; ++r) {
                        const float ext = mq[qg] * mkk[r];
                        st[f][qg][r] = ext * st[f][qg][r] - (1.0f - ext) * 1e9f;
                    }
            }
        }

        // __expf (no shift), lane-partial sums, pack P
#pragma unroll
        for (int qg = 0; qg < 2; ++qg) {
#pragma unroll
            for (int f = 0; f < 4; ++f) {
                float p0 = __expf(st[f][qg][0]);
                float p1 = __expf(st[f][qg][1]);
                float p2 = __expf(st[f][qg][2]);
                float p3 = __expf(st[f][qg][3]);
                l_i[qg] += (p0 + p1) + (p2 + p3);
                bf16x4 pk = {(bf16)p0, (bf16)p1, (bf16)p2, (bf16)p3};
                *(bf16x4*)&Ps[w * 32 + qg * 16 + l16][f * 16 + quad * 4] = pk;
            }
        }

        // O^T += V^T.P^T (Ps rows wave-local: no barrier)
        bf16x8 pb[2][2];
#pragma unroll
        for (int qg = 0; qg < 2; ++qg)
#pragma unroll
            for (int hf = 0; hf < 2; ++hf)
                pb[qg][hf] =
                    *(bf16x8*)&Ps[w * 32 + qg * 16 + l16][hf * 32 + quad * 8];
#pragma unroll
        for (int fd = 0; fd < 4; ++fd) {
            const bf16* vrow = &Vts[cur][fd * 16 + l16][0];
            bf16x8 va0 = *(const bf16x8*)(vrow + ((quad ^ swz) << 3));
            bf16x8 va1 = *(const bf16x8*)(vrow + (((4 + quad) ^ swz) << 3));
#pragma unroll
            for (int qg = 0; qg < 2; ++qg) {
                f32x4 c = acc[fd][qg];
                c = __builtin_amdgcn_mfma_f32_16x16x32_bf16(va0, pb[qg][0], c, 0, 0, 0);
                c = __builtin_amdgcn_mfma_f32_16x16x32_bf16(va1, pb[qg][1], c, 0, 0, 0);
                acc[fd][qg] = c;
            }
        }
    }

    // final row-sum reduction across quads (query id = l16 only)
#pragma unroll
    for (int qg = 0; qg < 2; ++qg) {
        l_i[qg] += __shfl_xor(l_i[qg], 16);
        l_i[qg] += __shfl_xor(l_i[qg], 32);
    }

    // epilogue: ctx fp32 [B*S][768]
#pragma unroll
    for (int qg = 0; qg < 2; ++qg) {
        const float inv = 1.0f / l_i[qg];
        const size_t row = (size_t)b * SEQ + qt * 128 + w * 32 + qg * 16 + l16;
#pragma unroll
        for (int fd = 0; fd < 4; ++fd) {
            float4 o = {acc[fd][qg][0] * inv, acc[fd][qg][1] * inv,
                        acc[fd][qg][2] * inv, acc[fd][qg][3] * inv};
            *(float4*)(ctx + row * HIDDEN + h * 64 + fd * 16 + quad * 4) = o;
        }
    }
}

// ---------------------------------------------------------------------------
// Output GEMM (R8 verbatim): 3-term split, 128m x 64n tile. A = ctx fp32,
// hi/lo split during staging (register prefetch); B = Wot hi/lo via
// global_load_lds into unpadded [64][32]. Epilogue: +bo, erf GELU.
// ---------------------------------------------------------------------------
__global__ __launch_bounds__(256) void gemm_out(const float* __restrict__ ctx,
                                                const bf16* __restrict__ Bhi,
                                                const bf16* __restrict__ Blo,
                                                const float* __restrict__ bo,
                                                float* __restrict__ fout) {
    __shared__ bf16 As_hi[128][40];
    __shared__ bf16 As_lo[128][40];
    __shared__ bf16 Bs_hi[64][32];
    __shared__ bf16 Bs_lo[64][32];

    const int tid = threadIdx.x;
    const int ln = tid & 63, wv = tid >> 6;
    const int quad = ln >> 4, l16 = ln & 15;
    const int wm = wv >> 1, wn = wv & 1;
    const int n0 = blockIdx.x * 64, m0 = blockIdx.y * 128;

    f32x4 acc[4][2];
#pragma unroll
    for (int i = 0; i < 4; ++i)
#pragma unroll
        for (int j = 0; j < 2; ++j) acc[i][j] = (f32x4){0.f, 0.f, 0.f, 0.f};

    const int sra = tid >> 1, sca = (tid & 1) << 4;
    const float* gA = ctx + (size_t)(m0 + sra) * HIDDEN + sca;
    const int drb = tid >> 2, dcb = (tid & 3) << 3;
    const bf16* gBh = Bhi + (size_t)(n0 + drb) * HIDDEN + dcb;
    const bf16* gBl = Blo + (size_t)(n0 + drb) * HIDDEN + dcb;
    bf16* lBh = (bf16*)Bs_hi + tid * 8;
    bf16* lBl = (bf16*)Bs_lo + tid * 8;

    float fa[16];
#pragma unroll
    for (int j = 0; j < 4; ++j) *(float4*)&fa[4 * j] = *(const float4*)(gA + 4 * j);

    for (int k0 = 0; k0 < HIDDEN; k0 += 32) {
        bf16 hi[16], lo[16];
#pragma unroll
        for (int j = 0; j < 16; ++j) {
            hi[j] = (bf16)fa[j];
            lo[j] = (bf16)(fa[j] - (float)hi[j]);
        }
        __syncthreads();
        load_lds16(gBh + k0, lBh);
        load_lds16(gBl + k0, lBl);
        *(bf16x8*)&As_hi[sra][sca] = *(bf16x8*)&hi[0];
        *(bf16x8*)&As_hi[sra][sca + 8] = *(bf16x8*)&hi[8];
        *(bf16x8*)&As_lo[sra][sca] = *(bf16x8*)&lo[0];
        *(bf16x8*)&As_lo[sra][sca + 8] = *(bf16x8*)&lo[8];
        __syncthreads();
        if (k0 + 32 < HIDDEN) {
#pragma unroll
            for (int j = 0; j < 4; ++j)
                *(float4*)&fa[4 * j] = *(const float4*)(gA + k0 + 32 + 4 * j);
        }

        bf16x8 ah[4], al[4], bh[2], bl[2];
#pragma unroll
        for (int i = 0; i < 4; ++i) {
            ah[i] = *(bf16x8*)&As_hi[wm * 64 + i * 16 + l16][quad * 8];
            al[i] = *(bf16x8*)&As_lo[wm * 64 + i * 16 + l16][quad * 8];
        }
#pragma unroll
        for (int i = 0; i < 2; ++i) {
            bh[i] = *(bf16x8*)&Bs_hi[wn * 32 + i * 16 + l16][quad * 8];
            bl[i] = *(bf16x8*)&Bs_lo[wn * 32 + i * 16 + l16][quad * 8];
        }
#pragma unroll
        for (int mi = 0; mi < 4; ++mi)
#pragma unroll
            for (int ni = 0; ni < 2; ++ni) {
                f32x4 c = acc[mi][ni];
                c = __builtin_amdgcn_mfma_f32_16x16x32_bf16(ah[mi], bh[ni], c, 0, 0, 0);
                c = __builtin_amdgcn_mfma_f32_16x16x32_bf16(ah[mi], bl[ni], c, 0, 0, 0);
                c = __builtin_amdgcn_mfma_f32_16x16x32_bf16(al[mi], bh[ni], c, 0, 0, 0);
                acc[mi][ni] = c;
            }
    }

#pragma unroll
    for (int ni = 0; ni < 2; ++ni) {
        const int n = n0 + wn * 32 + ni * 16 + l16;
        const float bb = bo[n];
#pragma unroll
        for (int mi = 0; mi < 4; ++mi)
#pragma unroll
            for (int r = 0; r < 4; ++r) {
                const int m = m0 + wm * 64 + mi * 16 + quad * 4 + r;
                float x = acc[mi][ni][r] + bb;
                x = 0.5f * x * (1.0f + erff(x * 0.70710678118654752440f));
                fout[(size_t)m * HIDDEN + n] = x;
            }
    }
}

// ---------------------------------------------------------------------------
extern "C" void kernel_launch(void* const* d_in, const int* in_sizes, int n_in,
                              void* d_out, int out_size, void* d_ws, size_t ws_size,
                              hipStream_t stream) {
    const float* X    = (const float*)d_in[0];
    const float* mask = (const float*)d_in[1];
    const float* Wq   = (const float*)d_in[2];
    const float* bq   = (const float*)d_in[3];
    const float* Wk   = (const float*)d_in[4];
    const float* bk   = (const float*)d_in[5];
    const float* Wv   = (const float*)d_in[6];
    const float* bv   = (const float*)d_in[7];
    const float* Wo   = (const float*)d_in[8];
    const float* bo   = (const float*)d_in[9];
    float* out = (float*)d_out;

    char* w = (char*)d_ws;
    const size_t NE = (size_t)BATCH * SEQ * HIDDEN;  // 6.29M elems
    bf16* q_ws   = (bf16*)w;  w += NE * 2;
    bf16* k_ws   = (bf16*)w;  w += NE * 2;
    bf16* vt_ws  = (bf16*)w;  w += NE * 2;
    float* ctx   = (float*)w; w += NE * 4;
    bf16* Xb     = (bf16*)w;  w += NE * 2;
    bf16* Wt     = (bf16*)w;  w += (size_t)3 * HIDDEN * HIDDEN * 2;
    bf16* Wot_hi = (bf16*)w;  w += (size_t)HIDDEN * HIDDEN * 2;
    bf16* Wot_lo = (bf16*)w;  w += (size_t)HIDDEN * HIDDEN * 2;

    prep_x<<<(int)(NE / 2048), 256, 0, stream>>>(X, Xb);
    prep_w<<<dim3(12, 12, 4), 256, 0, stream>>>(Wq, Wk, Wv, Wo, Wt, Wot_hi,
                                                Wot_lo);
    gemm_qkv<<<dim3(18, 64), 256, 0, stream>>>(Xb, Wt, bq, bk, bv, q_ws, k_ws,
                                               vt_ws);
    attn_mfma<<<dim3(SEQ / 128, NH, BATCH), 256, 0, stream>>>(q_ws, k_ws, vt_ws,
                                                              mask, ctx);
    gemm_out<<<dim3(12, 64), 256, 0, stream>>>(ctx, Wot_hi, Wot_lo, bo, out);
}